// Round 1
// baseline (310.934 us; speedup 1.0000x reference)
//
#include <hip/hip_runtime.h>

typedef _Float16 f16;
typedef f16  f16x8  __attribute__((ext_vector_type(8)));
typedef f16  f16x4  __attribute__((ext_vector_type(4)));
typedef float f32x16 __attribute__((ext_vector_type(16)));

#define B_   512
#define N_   2048
#define F_   16
#define C_   128
#define TP   128
#define PADV -10000.0f

// swizzled byte offset into a [128][128] f16 LDS tile (16B chunks XORed by row)
__device__ __forceinline__ int h_off(int row, int k) {
    return (row << 8) + ((((k >> 3) ^ row) & 15) << 4) + ((k & 7) << 1);
}

// ---- weight conversion: phi weights fp32 [K][128] -> f16 transposed [128][K] ----
// out layout (f16): Wt0 [128][16] at 0 | Wt1 [128][128] at 2048 | Wt2 at 18432 | Wt3 at 34816
__global__ void convert_weights(const float* __restrict__ w0, const float* __restrict__ w1,
                                const float* __restrict__ w2, const float* __restrict__ w3,
                                f16* __restrict__ out)
{
    int i = blockIdx.x * 256 + threadIdx.x;   // 51200 total
    float v;
    if (i < 2048) {
        int n = i >> 4, k = i & 15;
        v = w0[k * 128 + n];
    } else {
        int j = i - 2048;
        int l = j >> 14, r = j & 16383;
        int n = r >> 7, k = r & 127;
        const float* w = (l == 0) ? w1 : (l == 1) ? w2 : w3;
        v = w[k * 128 + n];
    }
    out[i] = (f16)v;
}

// ---- fused phi (4 layers, f16 MFMA) + masked sum-pool ----
__global__ __launch_bounds__(256, 2) void phi_pool_kernel(
    const float* __restrict__ x,
    const f16*  __restrict__ wtbuf,
    const float* __restrict__ pb0, const float* __restrict__ pb1,
    const float* __restrict__ pb2, const float* __restrict__ pb3,
    float* __restrict__ pooled)
{
    __shared__ unsigned char lds[65536];
    unsigned char* HbB = lds;                 // h tile, swizzled [128][128] f16
    unsigned char* WbB = lds + 32768;         // Wt tile, swizzled [128][128] f16
    f16* Hbf = (f16*)lds;                     // layer-0 x view: [128][24] f16
    f16* Wbf = (f16*)(lds + 32768);           // layer-0 Wt0 view: [128][24] f16

    const int tid  = threadIdx.x;
    const int lane = tid & 63;
    const int wv   = tid >> 6;
    const int l31  = lane & 31;
    const int q    = lane >> 5;
    const int b    = blockIdx.x >> 4;
    const int pt0  = (blockIdx.x & 15) * TP;

    const int ptBase = (wv >> 1) * 64;
    const int chBase = (wv & 1) * 64;

    // P0: stage x tile (fp32 -> f16) into Hb[0:6144) as [128][24]
    {
        const int pt = tid >> 1, hh = (tid & 1) * 8;
        const float* src = x + ((size_t)b * N_ + (size_t)(pt0 + pt)) * F_ + hh;
        float4 v0 = ((const float4*)src)[0];
        float4 v1 = ((const float4*)src)[1];
        f16x8 o;
        o[0] = (f16)v0.x; o[1] = (f16)v0.y; o[2] = (f16)v0.z; o[3] = (f16)v0.w;
        o[4] = (f16)v1.x; o[5] = (f16)v1.y; o[6] = (f16)v1.z; o[7] = (f16)v1.w;
        *(f16x8*)(Hbf + pt * 24 + hh) = o;
    }
    // P0b: stage Wt0 [128][16] -> Wb as [128][24]
    {
        const int ch = tid >> 1, hh = (tid & 1) * 8;
        f16x8 w = *(const f16x8*)(wtbuf + tid * 8);
        *(f16x8*)(Wbf + ch * 24 + hh) = w;
    }
    __syncthreads();

    // P1: per-row validity bitmask via ballot (each wave computes both 64-bit words)
    unsigned long long mvalid0, mvalid1;
    {
        bool v0p, v1p;
        {
            f16x8 a = *(const f16x8*)(Hbf + lane * 24);
            f16x8 c2 = *(const f16x8*)(Hbf + lane * 24 + 8);
            bool pad = true;
            #pragma unroll
            for (int j = 0; j < 8; ++j)
                pad = pad && ((float)a[j] == PADV) && ((float)c2[j] == PADV);
            v0p = !pad;
        }
        {
            f16x8 a = *(const f16x8*)(Hbf + (lane + 64) * 24);
            f16x8 c2 = *(const f16x8*)(Hbf + (lane + 64) * 24 + 8);
            bool pad = true;
            #pragma unroll
            for (int j = 0; j < 8; ++j)
                pad = pad && ((float)a[j] == PADV) && ((float)c2[j] == PADV);
            v1p = !pad;
        }
        mvalid0 = __ballot(v0p);
        mvalid1 = __ballot(v1p);
    }

    f32x16 acc[2][2];
    #pragma unroll
    for (int p = 0; p < 2; ++p)
        #pragma unroll
        for (int c = 0; c < 2; ++c)
            #pragma unroll
            for (int r = 0; r < 16; ++r)
                acc[p][c][r] = 0.f;

    // M0: layer 0 (K=16), orientation 2: D[ch][pt] = sum_k Wt0[ch][k] * x[pt][k]
    {
        f16x8 bfr[2], afr[2];
        #pragma unroll
        for (int p = 0; p < 2; ++p)
            bfr[p] = *(const f16x8*)(Hbf + (ptBase + p * 32 + l31) * 24 + q * 8);
        #pragma unroll
        for (int c = 0; c < 2; ++c)
            afr[c] = *(const f16x8*)(Wbf + (chBase + c * 32 + l31) * 24 + q * 8);
        #pragma unroll
        for (int p = 0; p < 2; ++p)
            #pragma unroll
            for (int c = 0; c < 2; ++c)
                acc[p][c] = __builtin_amdgcn_mfma_f32_32x32x16_f16(afr[c], bfr[p], acc[p][c], 0, 0, 0);
    }
    __syncthreads();

    const float* pbs[4] = {pb0, pb1, pb2, pb3};

    #pragma unroll 1
    for (int l = 1; l <= 3; ++l) {
        // S: epilogue of layer l-1 -> Hb (bias fp32 + relu + f16), stage Wt_l -> Wb
        {
            const float* bias_prev = pbs[l - 1];
            #pragma unroll
            for (int c = 0; c < 2; ++c) {
                #pragma unroll
                for (int g = 0; g < 4; ++g) {
                    const int chS = chBase + c * 32 + 8 * g + 4 * q;
                    float4 b4 = *(const float4*)(bias_prev + chS);
                    #pragma unroll
                    for (int p = 0; p < 2; ++p) {
                        const int pt = ptBase + p * 32 + l31;
                        f16x4 ov;
                        ov[0] = (f16)fmaxf(acc[p][c][4 * g + 0] + b4.x, 0.f);
                        ov[1] = (f16)fmaxf(acc[p][c][4 * g + 1] + b4.y, 0.f);
                        ov[2] = (f16)fmaxf(acc[p][c][4 * g + 2] + b4.z, 0.f);
                        ov[3] = (f16)fmaxf(acc[p][c][4 * g + 3] + b4.w, 0.f);
                        *(f16x4*)(HbB + h_off(pt, chS)) = ov;
                    }
                }
            }
            const f16* wl = wtbuf + 2048 + (l - 1) * 16384;
            #pragma unroll
            for (int i = 0; i < 8; ++i) {
                int c = tid + i * 256;
                int ch = c >> 4, kb = c & 15;
                f16x8 w = *(const f16x8*)(wl + ch * 128 + kb * 8);
                *(f16x8*)(WbB + h_off(ch, kb * 8)) = w;
            }
            #pragma unroll
            for (int p = 0; p < 2; ++p)
                #pragma unroll
                for (int c = 0; c < 2; ++c)
                    #pragma unroll
                    for (int r = 0; r < 16; ++r)
                        acc[p][c][r] = 0.f;
        }
        __syncthreads();

        // M: K=128, 8 k-steps. Layers 1-2 orientation 2; layer 3 orientation 1 (D[pt][ch])
        {
            const bool swapAB = (l == 3);
            #pragma unroll
            for (int ks = 0; ks < 8; ++ks) {
                const int k = ks * 16 + q * 8;
                f16x8 bfr[2], afr[2];
                #pragma unroll
                for (int p = 0; p < 2; ++p)
                    bfr[p] = *(const f16x8*)(HbB + h_off(ptBase + p * 32 + l31, k));
                #pragma unroll
                for (int c = 0; c < 2; ++c)
                    afr[c] = *(const f16x8*)(WbB + h_off(chBase + c * 32 + l31, k));
                if (!swapAB) {
                    #pragma unroll
                    for (int p = 0; p < 2; ++p)
                        #pragma unroll
                        for (int c = 0; c < 2; ++c)
                            acc[p][c] = __builtin_amdgcn_mfma_f32_32x32x16_f16(afr[c], bfr[p], acc[p][c], 0, 0, 0);
                } else {
                    #pragma unroll
                    for (int p = 0; p < 2; ++p)
                        #pragma unroll
                        for (int c = 0; c < 2; ++c)
                            acc[p][c] = __builtin_amdgcn_mfma_f32_32x32x16_f16(bfr[p], afr[c], acc[p][c], 0, 0, 0);
                }
            }
        }
        __syncthreads();
    }

    // Pool: layer-3 epilogue (orientation 1: col=ch=lane&31, row=pt), masked sum over pts
    {
        const unsigned long long mw = ptBase ? mvalid1 : mvalid0;
        float sums[2];
        #pragma unroll
        for (int c = 0; c < 2; ++c) {
            const int ch = chBase + c * 32 + l31;
            const float bch = pb3[ch];
            float s = 0.f;
            #pragma unroll
            for (int p = 0; p < 2; ++p) {
                #pragma unroll
                for (int r = 0; r < 16; ++r) {
                    const int pt = p * 32 + (r & 3) + 8 * (r >> 2) + 4 * q;  // within wave's 64
                    const bool valid = (mw >> pt) & 1ull;
                    float vv = fmaxf(acc[p][c][r] + bch, 0.f);
                    s += valid ? vv : 0.f;   // select (NaN-safe for pad rows)
                }
            }
            s += __shfl_xor(s, 32);
            sums[c] = s;
        }
        const int ch = chBase + q * 32 + l31;
        atomicAdd(&pooled[b * C_ + ch], q ? sums[1] : sums[0]);
    }
}

// ---- rho: fp32 MLP on pooled [512][128] -> out [512] ----
__global__ __launch_bounds__(128) void rho_kernel(
    const float* __restrict__ pooled,
    const float* __restrict__ w0, const float* __restrict__ b0,
    const float* __restrict__ w1, const float* __restrict__ b1,
    const float* __restrict__ w2, const float* __restrict__ b2,
    const float* __restrict__ w3, const float* __restrict__ b3,
    float* __restrict__ out)
{
    __shared__ float buf[2][128];
    __shared__ float red[2];
    const int b = blockIdx.x, t = threadIdx.x;
    buf[0][t] = pooled[b * 128 + t];
    __syncthreads();
    const float* ws3[3] = {w0, w1, w2};
    const float* bs3[3] = {b0, b1, b2};
    int cur = 0;
    #pragma unroll 1
    for (int l = 0; l < 3; ++l) {
        float acc = bs3[l][t];
        const float* w = ws3[l];
        #pragma unroll 8
        for (int k = 0; k < 128; ++k)
            acc = fmaf(buf[cur][k], w[k * 128 + t], acc);
        buf[cur ^ 1][t] = fmaxf(acc, 0.f);
        cur ^= 1;
        __syncthreads();
    }
    float v = buf[cur][t] * w3[t];
    #pragma unroll
    for (int off = 32; off > 0; off >>= 1)
        v += __shfl_down(v, off, 64);
    if ((t & 63) == 0) red[t >> 6] = v;
    __syncthreads();
    if (t == 0) out[b] = red[0] + red[1] + b3[0];
}

extern "C" void kernel_launch(void* const* d_in, const int* in_sizes, int n_in,
                              void* d_out, int out_size, void* d_ws, size_t ws_size,
                              hipStream_t stream)
{
    (void)in_sizes; (void)n_in; (void)out_size; (void)ws_size;
    const float* x      = (const float*)d_in[0];
    const float* phi_w0 = (const float*)d_in[1];
    const float* phi_b0 = (const float*)d_in[2];
    const float* phi_w1 = (const float*)d_in[3];
    const float* phi_b1 = (const float*)d_in[4];
    const float* phi_w2 = (const float*)d_in[5];
    const float* phi_b2 = (const float*)d_in[6];
    const float* phi_w3 = (const float*)d_in[7];
    const float* phi_b3 = (const float*)d_in[8];
    const float* rho_w0 = (const float*)d_in[9];
    const float* rho_b0 = (const float*)d_in[10];
    const float* rho_w1 = (const float*)d_in[11];
    const float* rho_b1 = (const float*)d_in[12];
    const float* rho_w2 = (const float*)d_in[13];
    const float* rho_b2 = (const float*)d_in[14];
    const float* rho_w3 = (const float*)d_in[15];
    const float* rho_b3 = (const float*)d_in[16];

    float* pooled = (float*)d_ws;                          // 512*128*4 = 262144 B
    f16*   wtbuf  = (f16*)((char*)d_ws + 262144);          // 51200 f16 = 102400 B

    hipMemsetAsync(pooled, 0, B_ * C_ * sizeof(float), stream);
    convert_weights<<<200, 256, 0, stream>>>(phi_w0, phi_w1, phi_w2, phi_w3, wtbuf);
    phi_pool_kernel<<<B_ * (N_ / TP), 256, 0, stream>>>(x, wtbuf, phi_b0, phi_b1, phi_b2, phi_b3, pooled);
    rho_kernel<<<B_, 128, 0, stream>>>(pooled, rho_w0, rho_b0, rho_w1, rho_b1,
                                       rho_w2, rho_b2, rho_w3, rho_b3, (float*)d_out);
}

// Round 2
// 283.239 us; speedup vs baseline: 1.0978x; 1.0978x over previous
//
#include <hip/hip_runtime.h>

typedef _Float16 f16;
typedef f16  f16x4  __attribute__((ext_vector_type(4)));
typedef f16  f16x8  __attribute__((ext_vector_type(8)));
typedef float f32x16 __attribute__((ext_vector_type(16)));

#define B_   512
#define N_   2048
#define PADV -10000.0f

// wtbuf layout (f16): W0t [128 out][16 in] at 0 | Wt1 [128][128] at 2048
//                     | Wt2 at 18432 | Wt3 at 34816   (all [out_ch][in_ch] row-major)

// ---- prep: convert phi weights fp32 -> f16 transposed, zero pooled ----
__global__ void prep_kernel(const float* __restrict__ w0, const float* __restrict__ w1,
                            const float* __restrict__ w2, const float* __restrict__ w3,
                            f16* __restrict__ out, float* __restrict__ pooled)
{
    int i = blockIdx.x * 256 + threadIdx.x;   // grid 256*256 = 65536
    if (i < 2048) {
        out[i] = (f16)w0[(i & 15) * 128 + (i >> 4)];
    } else if (i < 51200) {
        int j = i - 2048;
        int l = j >> 14, r = j & 16383;
        const float* w = (l == 0) ? w1 : (l == 1) ? w2 : w3;
        out[i] = (f16)w[(r & 127) * 128 + (r >> 7)];
    }
    pooled[i] = 0.f;   // 512*128 = 65536
}

// swizzled byte offset into a [128 row][16 chunk] 16B-chunk weight tile
__device__ __forceinline__ int swz(int row, int chunk) {
    return row * 256 + ((chunk ^ (row & 15)) << 4);
}

__device__ __forceinline__ void gl_lds16(const void* g, void* l) {
    __builtin_amdgcn_global_load_lds(
        (const __attribute__((address_space(1))) void*)g,
        (__attribute__((address_space(3))) void*)l, 16, 0, 0);
}

// epilogue: acc in D[ch][pt] layout -> bias+relu+f16 -> next-layer B-frags (h in regs)
__device__ __forceinline__ void epilogue_to_bfrag(const f32x16 acc[4], const float* __restrict__ bias,
                                                  int q, f16x8 hf[8])
{
    f16x4 pk[16];
    #pragma unroll
    for (int g = 0; g < 16; ++g) {
        float4 b4 = *(const float4*)(bias + 8 * g + 4 * q);   // ch = 8g+4q+t
        const int c = g >> 2, r0 = (g & 3) * 4;
        f16x4 p;
        p[0] = (f16)fmaxf(acc[c][r0 + 0] + b4.x, 0.f);
        p[1] = (f16)fmaxf(acc[c][r0 + 1] + b4.y, 0.f);
        p[2] = (f16)fmaxf(acc[c][r0 + 2] + b4.z, 0.f);
        p[3] = (f16)fmaxf(acc[c][r0 + 3] + b4.w, 0.f);
        pk[g] = p;
    }
    #pragma unroll
    for (int s = 0; s < 8; ++s) {
        // q=0 sends pk[2s+1], needs partner's pk[2s]; q=1 sends pk[2s], needs pk[2s+1]
        f16x4 own = q ? pk[2 * s] : pk[2 * s + 1];
        long long t = __shfl_xor(__builtin_bit_cast(long long, own), 32);
        f16x4 rec = __builtin_bit_cast(f16x4, t);
        f16x4 lo = q ? rec : pk[2 * s];
        f16x4 hi = q ? pk[2 * s + 1] : rec;
        f16x8 h;
        h[0] = lo[0]; h[1] = lo[1]; h[2] = lo[2]; h[3] = lo[3];
        h[4] = hi[0]; h[5] = hi[1]; h[6] = hi[2]; h[7] = hi[3];
        hf[s] = h;
    }
}

// ---- fused phi (4 layers, f16 MFMA, h in registers) + masked sum-pool ----
__global__ __launch_bounds__(512, 4) void phi_pool_kernel(
    const float* __restrict__ x,
    const f16*  __restrict__ wtbuf,
    const float* __restrict__ pb0, const float* __restrict__ pb1,
    const float* __restrict__ pb2, const float* __restrict__ pb3,
    float* __restrict__ pooled)
{
    __shared__ f16 wA[16384];   // 32 KB, swizzled [128][128]
    __shared__ f16 wB[16384];   // 32 KB

    const int tid  = threadIdx.x;
    const int lane = tid & 63;
    const int wv   = tid >> 6;          // 8 waves
    const int l31  = lane & 31;
    const int q    = lane >> 5;
    const int b    = blockIdx.x >> 3;
    const int pt0  = (blockIdx.x & 7) * 256 + wv * 32;   // wave's 32-pt tile
    const int pt   = pt0 + l31;

    // async stage: L1 weights -> wA, L2 -> wB (each wave: rows [16wv,16wv+16))
    {
        const f16* wl1 = wtbuf + 2048;
        const f16* wl2 = wtbuf + 2048 + 16384;
        #pragma unroll
        for (int i = 0; i < 4; ++i) {
            const int row   = wv * 16 + i * 4 + (lane >> 4);
            const int chunk = (lane & 15) ^ (row & 15);
            const int loff  = (wv * 16 + i * 4) * 256;     // uniform region base (bytes)
            gl_lds16(wl1 + row * 128 + chunk * 8, (char*)wA + loff);
            gl_lds16(wl2 + row * 128 + chunk * 8, (char*)wB + loff);
        }
    }

    // load x row (all 16 features), validity, build layer-0 B-frag
    unsigned mask32;
    f16x8 hf[8];
    {
        const float* xr = x + (size_t)(b * N_ + pt) * 16;
        float4 v0 = ((const float4*)xr)[0];
        float4 v1 = ((const float4*)xr)[1];
        float4 v2 = ((const float4*)xr)[2];
        float4 v3 = ((const float4*)xr)[3];
        bool vld = (v0.x != PADV) || (v0.y != PADV) || (v0.z != PADV) || (v0.w != PADV) ||
                   (v1.x != PADV) || (v1.y != PADV) || (v1.z != PADV) || (v1.w != PADV) ||
                   (v2.x != PADV) || (v2.y != PADV) || (v2.z != PADV) || (v2.w != PADV) ||
                   (v3.x != PADV) || (v3.y != PADV) || (v3.z != PADV) || (v3.w != PADV);
        mask32 = (unsigned)(__ballot(vld) & 0xffffffffull);
        float4 a0 = q ? v2 : v0;
        float4 a1 = q ? v3 : v1;
        f16x8 h0;
        h0[0] = (f16)a0.x; h0[1] = (f16)a0.y; h0[2] = (f16)a0.z; h0[3] = (f16)a0.w;
        h0[4] = (f16)a1.x; h0[5] = (f16)a1.y; h0[6] = (f16)a1.z; h0[7] = (f16)a1.w;
        hf[0] = h0;
    }

    f32x16 acc[4];
    #pragma unroll
    for (int c = 0; c < 4; ++c)
        #pragma unroll
        for (int r = 0; r < 16; ++r) acc[c][r] = 0.f;

    // L0: D[ch][pt], K=16, A = W0t straight from global (L2-hot, coalesced 1KB/inst)
    {
        f16x8 h0 = hf[0];
        #pragma unroll
        for (int c = 0; c < 4; ++c) {
            f16x8 af = *(const f16x8*)(wtbuf + (32 * c + l31) * 16 + q * 8);
            acc[c] = __builtin_amdgcn_mfma_f32_32x32x16_f16(af, h0, acc[c], 0, 0, 0);
        }
    }
    epilogue_to_bfrag(acc, pb0, q, hf);

    __syncthreads();   // wA (L1) + wB (L2) staged

    // L1: D[ch][pt], A = Wt1 from wA, B = h in regs
    #pragma unroll
    for (int c = 0; c < 4; ++c)
        #pragma unroll
        for (int r = 0; r < 16; ++r) acc[c][r] = 0.f;
    #pragma unroll
    for (int s = 0; s < 8; ++s) {
        #pragma unroll
        for (int c = 0; c < 4; ++c) {
            f16x8 wf = *(const f16x8*)((const char*)wA + swz(32 * c + l31, 2 * s + q));
            acc[c] = __builtin_amdgcn_mfma_f32_32x32x16_f16(wf, hf[s], acc[c], 0, 0, 0);
        }
    }
    epilogue_to_bfrag(acc, pb1, q, hf);

    __syncthreads();   // everyone done reading wA

    // async stage: L3 weights -> wA
    {
        const f16* wl3 = wtbuf + 2048 + 32768;
        #pragma unroll
        for (int i = 0; i < 4; ++i) {
            const int row   = wv * 16 + i * 4 + (lane >> 4);
            const int chunk = (lane & 15) ^ (row & 15);
            const int loff  = (wv * 16 + i * 4) * 256;
            gl_lds16(wl3 + row * 128 + chunk * 8, (char*)wA + loff);
        }
    }

    // L2: D[ch][pt], A = Wt2 from wB
    #pragma unroll
    for (int c = 0; c < 4; ++c)
        #pragma unroll
        for (int r = 0; r < 16; ++r) acc[c][r] = 0.f;
    #pragma unroll
    for (int s = 0; s < 8; ++s) {
        #pragma unroll
        for (int c = 0; c < 4; ++c) {
            f16x8 wf = *(const f16x8*)((const char*)wB + swz(32 * c + l31, 2 * s + q));
            acc[c] = __builtin_amdgcn_mfma_f32_32x32x16_f16(wf, hf[s], acc[c], 0, 0, 0);
        }
    }
    epilogue_to_bfrag(acc, pb2, q, hf);

    __syncthreads();   // L3 staged (vmcnt drained), wB free

    // L3: swapped orientation D[pt][ch]: A = h (same frag layout), B = Wt3 rows from wA
    #pragma unroll
    for (int c = 0; c < 4; ++c)
        #pragma unroll
        for (int r = 0; r < 16; ++r) acc[c][r] = 0.f;
    #pragma unroll
    for (int s = 0; s < 8; ++s) {
        #pragma unroll
        for (int c = 0; c < 4; ++c) {
            f16x8 wf = *(const f16x8*)((const char*)wA + swz(32 * c + l31, 2 * s + q));
            acc[c] = __builtin_amdgcn_mfma_f32_32x32x16_f16(hf[s], wf, acc[c], 0, 0, 0);
        }
    }

    // pool: lane holds ch = 32c+l31, rows are pts; masked select + cross-q reduce
    {
        #pragma unroll
        for (int c = 0; c < 4; ++c) {
            const float bch = pb3[32 * c + l31];
            float s = 0.f;
            #pragma unroll
            for (int r = 0; r < 16; ++r) {
                const int ptl = (r & 3) + 8 * (r >> 2) + 4 * q;
                const bool valid = (mask32 >> ptl) & 1u;
                float vv = fmaxf(acc[c][r] + bch, 0.f);
                s += valid ? vv : 0.f;    // select, NaN-safe for pad rows
            }
            s += __shfl_xor(s, 32);
            if (q == 0) atomicAdd(&pooled[b * 128 + 32 * c + l31], s);
        }
    }
}

// ---- rho: fp32 MLP on pooled [512][128] -> out [512] ----
__global__ __launch_bounds__(128) void rho_kernel(
    const float* __restrict__ pooled,
    const float* __restrict__ w0, const float* __restrict__ b0,
    const float* __restrict__ w1, const float* __restrict__ b1,
    const float* __restrict__ w2, const float* __restrict__ b2,
    const float* __restrict__ w3, const float* __restrict__ b3,
    float* __restrict__ out)
{
    __shared__ float buf[2][128];
    __shared__ float red[2];
    const int b = blockIdx.x, t = threadIdx.x;
    buf[0][t] = pooled[b * 128 + t];
    __syncthreads();
    const float* ws3[3] = {w0, w1, w2};
    const float* bs3[3] = {b0, b1, b2};
    int cur = 0;
    #pragma unroll 1
    for (int l = 0; l < 3; ++l) {
        float acc = bs3[l][t];
        const float* w = ws3[l];
        #pragma unroll 8
        for (int k = 0; k < 128; ++k)
            acc = fmaf(buf[cur][k], w[k * 128 + t], acc);
        buf[cur ^ 1][t] = fmaxf(acc, 0.f);
        cur ^= 1;
        __syncthreads();
    }
    float v = buf[cur][t] * w3[t];
    #pragma unroll
    for (int off = 32; off > 0; off >>= 1)
        v += __shfl_down(v, off, 64);
    if ((t & 63) == 0) red[t >> 6] = v;
    __syncthreads();
    if (t == 0) out[b] = red[0] + red[1] + b3[0];
}

extern "C" void kernel_launch(void* const* d_in, const int* in_sizes, int n_in,
                              void* d_out, int out_size, void* d_ws, size_t ws_size,
                              hipStream_t stream)
{
    (void)in_sizes; (void)n_in; (void)out_size; (void)ws_size;
    const float* x      = (const float*)d_in[0];
    const float* phi_w0 = (const float*)d_in[1];
    const float* phi_b0 = (const float*)d_in[2];
    const float* phi_w1 = (const float*)d_in[3];
    const float* phi_b1 = (const float*)d_in[4];
    const float* phi_w2 = (const float*)d_in[5];
    const float* phi_b2 = (const float*)d_in[6];
    const float* phi_w3 = (const float*)d_in[7];
    const float* phi_b3 = (const float*)d_in[8];
    const float* rho_w0 = (const float*)d_in[9];
    const float* rho_b0 = (const float*)d_in[10];
    const float* rho_w1 = (const float*)d_in[11];
    const float* rho_b1 = (const float*)d_in[12];
    const float* rho_w2 = (const float*)d_in[13];
    const float* rho_b2 = (const float*)d_in[14];
    const float* rho_w3 = (const float*)d_in[15];
    const float* rho_b3 = (const float*)d_in[16];

    float* pooled = (float*)d_ws;                          // 512*128*4 = 262144 B
    f16*   wtbuf  = (f16*)((char*)d_ws + 262144);          // 51200 f16 = 102400 B

    prep_kernel<<<256, 256, 0, stream>>>(phi_w0, phi_w1, phi_w2, phi_w3, wtbuf, pooled);
    phi_pool_kernel<<<4096, 512, 0, stream>>>(x, wtbuf, phi_b0, phi_b1, phi_b2, phi_b3, pooled);
    rho_kernel<<<B_, 128, 0, stream>>>(pooled, rho_w0, rho_b0, rho_w1, rho_b1,
                                       rho_w2, rho_b2, rho_w3, rho_b3, (float*)d_out);
}

// Round 4
// 226.009 us; speedup vs baseline: 1.3758x; 1.2532x over previous
//
#include <hip/hip_runtime.h>

typedef _Float16 f16;
typedef f16  f16x2  __attribute__((ext_vector_type(2)));
typedef f16  f16x8  __attribute__((ext_vector_type(8)));
typedef __fp16 h16x2 __attribute__((ext_vector_type(2)));
typedef float f32x16 __attribute__((ext_vector_type(16)));

#define B_   512
#define N_   2048
#define PADV -10000.0f

union F16x8 { f16x8 v; f16x2 h2[4]; };

__device__ __forceinline__ f16x2 pkrtz(float a, float b) {
    h16x2 r = __builtin_amdgcn_cvt_pkrtz(a, b);
    return __builtin_bit_cast(f16x2, r);
}

// wtbuf layout (f16): W0t [128 out][16 in] at 0 (natural in-order)
// Wt1/Wt2/Wt3 [128 out][128 slot] at 2048/18432/34816, where slot k is the
// PERMUTED input-channel order sigma(slot) matching the MFMA D-register layout:
//   s=slot>>4, q=(slot>>3)&1, j=slot&7
//   sigma = 32*(s>>1) + 16*(s&1) + 4*q + 8*(j>>2) + (j&3)
__global__ void prep_kernel(const float* __restrict__ w0, const float* __restrict__ w1,
                            const float* __restrict__ w2, const float* __restrict__ w3,
                            f16* __restrict__ out, float* __restrict__ pooled)
{
    int i = blockIdx.x * 256 + threadIdx.x;   // grid 256*256 = 65536
    if (i < 2048) {
        out[i] = (f16)w0[(i & 15) * 128 + (i >> 4)];
    } else if (i < 51200) {
        int j = i - 2048;
        int l = j >> 14, r = j & 16383;
        int o = r >> 7, slot = r & 127;
        int s = slot >> 4, qq = (slot >> 3) & 1, jj = slot & 7;
        int sig = 32 * (s >> 1) + 16 * (s & 1) + 4 * qq + 8 * (jj >> 2) + (jj & 3);
        const float* w = (l == 0) ? w1 : (l == 1) ? w2 : w3;
        out[i] = (f16)w[sig * 128 + o];
    }
    pooled[i] = 0.f;   // 512*128 = 65536
}

// swizzled byte offset into a [128 row][16 chunk] 16B-chunk weight tile
__device__ __forceinline__ int swz(int row, int chunk) {
    return row * 256 + ((chunk ^ (row & 15)) << 4);
}

__device__ __forceinline__ void gl_lds16(const void* g, void* l) {
    __builtin_amdgcn_global_load_lds(
        (const __attribute__((address_space(1))) void*)g,
        (__attribute__((address_space(3))) void*)l, 16, 0, 0);
}

// ---- fused phi (4 layers, f16 MFMA, h in registers, no shuffles) + masked pool ----
__global__ __launch_bounds__(256, 2) void phi_pool_kernel(
    const float* __restrict__ x,
    const f16*  __restrict__ wtbuf,
    const float* __restrict__ pb0, const float* __restrict__ pb1,
    const float* __restrict__ pb2, const float* __restrict__ pb3,
    float* __restrict__ pooled)
{
    __shared__ f16 wA[16384];   // 32 KB swizzled [128 out][128 slot]
    __shared__ f16 wB[16384];

    const int tid  = threadIdx.x;
    const int lane = tid & 63;
    const int wv   = tid >> 6;          // 4 waves
    const int l31  = lane & 31;
    const int q    = lane >> 5;
    const int b    = blockIdx.x >> 3;
    const int p0   = (blockIdx.x & 7) * 256 + wv * 64;   // wave's 64-pt tile

    // ---- x loads first (oldest vmcnt), 2 rows x 8 floats per lane ----
    const float* xp = x + ((size_t)b * N_ + (size_t)(p0 + l31)) * 16 + 8 * q;
    float4 a0 = ((const float4*)xp)[0];
    float4 a1 = ((const float4*)xp)[1];
    float4 c0 = ((const float4*)(xp + 512))[0];   // +32 rows
    float4 c1 = ((const float4*)(xp + 512))[1];

    // ---- W0 A-frags from global (L2-hot) ----
    f16x8 w0f[4];
    #pragma unroll
    for (int c = 0; c < 4; ++c)
        w0f[c] = *(const f16x8*)(wtbuf + (32 * c + l31) * 16 + 8 * q);

    // ---- async stage W1 -> wA, W2 -> wB (each wave rows [32wv, 32wv+32)) ----
    {
        const f16* wl1 = wtbuf + 2048;
        const f16* wl2 = wtbuf + 2048 + 16384;
        #pragma unroll
        for (int i = 0; i < 8; ++i) {
            const int row   = wv * 32 + i * 4 + (lane >> 4);
            const int chunk = (lane & 15) ^ (row & 15);
            const int loff  = (wv * 32 + i * 4) * 256;   // bytes, wave-uniform
            gl_lds16(wl1 + row * 128 + chunk * 8, (char*)wA + loff);
            gl_lds16(wl2 + row * 128 + chunk * 8, (char*)wB + loff);
        }
    }

    // ---- validity masks (row pad iff both 8-elem halves all PAD) ----
    bool vA = (a0.x != PADV) || (a0.y != PADV) || (a0.z != PADV) || (a0.w != PADV) ||
              (a1.x != PADV) || (a1.y != PADV) || (a1.z != PADV) || (a1.w != PADV);
    bool vB = (c0.x != PADV) || (c0.y != PADV) || (c0.z != PADV) || (c0.w != PADV) ||
              (c1.x != PADV) || (c1.y != PADV) || (c1.z != PADV) || (c1.w != PADV);
    unsigned long long blA = __ballot(vA), blB = __ballot(vB);
    const unsigned mA = (unsigned)blA | (unsigned)(blA >> 32);
    const unsigned mB = (unsigned)blB | (unsigned)(blB >> 32);

    // ---- layer-0 B-frags (k = 8q+j natural order) ----
    F16x8 hf[2][8];
    hf[0][0].h2[0] = pkrtz(a0.x, a0.y);
    hf[0][0].h2[1] = pkrtz(a0.z, a0.w);
    hf[0][0].h2[2] = pkrtz(a1.x, a1.y);
    hf[0][0].h2[3] = pkrtz(a1.z, a1.w);
    hf[1][0].h2[0] = pkrtz(c0.x, c0.y);
    hf[1][0].h2[1] = pkrtz(c0.z, c0.w);
    hf[1][0].h2[2] = pkrtz(c1.x, c1.y);
    hf[1][0].h2[3] = pkrtz(c1.z, c1.w);

    f32x16 acc[2][4];

    // bias pre-load into accumulator: acc[t][c][4g+e] = bias[32c + 8g + 4q + e]
    #define INIT_ACC_BIAS(pb)                                              \
        {                                                                  \
            _Pragma("unroll")                                              \
            for (int c = 0; c < 4; ++c) {                                  \
                _Pragma("unroll")                                          \
                for (int g = 0; g < 4; ++g) {                              \
                    float4 bb = *(const float4*)((pb) + 32 * c + 8 * g + 4 * q); \
                    const float* bbp = (const float*)&bb;                  \
                    _Pragma("unroll")                                      \
                    for (int e = 0; e < 4; ++e) {                          \
                        acc[0][c][4 * g + e] = bbp[e];                     \
                        acc[1][c][4 * g + e] = bbp[e];                     \
                    }                                                      \
                }                                                          \
            }                                                              \
        }

    // epilogue: packed cvt + relu; D regs ARE the next B-frag (weights permuted)
    #define EPILOGUE()                                                     \
        {                                                                  \
            const f16x2 z2 = {(f16)0.f, (f16)0.f};                         \
            _Pragma("unroll")                                              \
            for (int t = 0; t < 2; ++t) {                                  \
                _Pragma("unroll")                                          \
                for (int s = 0; s < 8; ++s) {                              \
                    const int c = s >> 1, r0 = 8 * (s & 1);                \
                    _Pragma("unroll")                                      \
                    for (int p = 0; p < 4; ++p) {                          \
                        f16x2 m = pkrtz(                                   \
                            acc[t][c][r0 + 2 * p], acc[t][c][r0 + 2 * p + 1]); \
                        hf[t][s].h2[p] = __builtin_elementwise_max(m, z2); \
                    }                                                      \
                }                                                          \
            }                                                              \
        }

    // ---- L0: D[ch][pt], K=16 ----
    INIT_ACC_BIAS(pb0);
    #pragma unroll
    for (int c = 0; c < 4; ++c) {
        acc[0][c] = __builtin_amdgcn_mfma_f32_32x32x16_f16(w0f[c], hf[0][0].v, acc[0][c], 0, 0, 0);
        acc[1][c] = __builtin_amdgcn_mfma_f32_32x32x16_f16(w0f[c], hf[1][0].v, acc[1][c], 0, 0, 0);
    }
    EPILOGUE();

    __syncthreads();   // staging of wA/wB complete

    // ---- L1: A = W1 from wA ----
    INIT_ACC_BIAS(pb1);
    #pragma unroll
    for (int s = 0; s < 8; ++s) {
        f16x8 wf[4];
        #pragma unroll
        for (int c = 0; c < 4; ++c)
            wf[c] = *(const f16x8*)((const char*)wA + swz(32 * c + l31, 2 * s + q));
        #pragma unroll
        for (int c = 0; c < 4; ++c) {
            acc[0][c] = __builtin_amdgcn_mfma_f32_32x32x16_f16(wf[c], hf[0][s].v, acc[0][c], 0, 0, 0);
            acc[1][c] = __builtin_amdgcn_mfma_f32_32x32x16_f16(wf[c], hf[1][s].v, acc[1][c], 0, 0, 0);
        }
    }

    __syncthreads();   // all waves done reading wA

    // ---- restage W3 -> wA (overlaps L1 epilogue + L2) ----
    {
        const f16* wl3 = wtbuf + 2048 + 32768;
        #pragma unroll
        for (int i = 0; i < 8; ++i) {
            const int row   = wv * 32 + i * 4 + (lane >> 4);
            const int chunk = (lane & 15) ^ (row & 15);
            const int loff  = (wv * 32 + i * 4) * 256;
            gl_lds16(wl3 + row * 128 + chunk * 8, (char*)wA + loff);
        }
    }

    EPILOGUE();   // L1 epilogue

    // ---- L2: A = W2 from wB ----
    INIT_ACC_BIAS(pb2);
    #pragma unroll
    for (int s = 0; s < 8; ++s) {
        f16x8 wf[4];
        #pragma unroll
        for (int c = 0; c < 4; ++c)
            wf[c] = *(const f16x8*)((const char*)wB + swz(32 * c + l31, 2 * s + q));
        #pragma unroll
        for (int c = 0; c < 4; ++c) {
            acc[0][c] = __builtin_amdgcn_mfma_f32_32x32x16_f16(wf[c], hf[0][s].v, acc[0][c], 0, 0, 0);
            acc[1][c] = __builtin_amdgcn_mfma_f32_32x32x16_f16(wf[c], hf[1][s].v, acc[1][c], 0, 0, 0);
        }
    }
    EPILOGUE();   // L2 epilogue

    __syncthreads();   // W3 staging drained

    // ---- L3: swapped orientation D[pt][ch]; bias = b3 broadcast along rows ----
    {
        float bL[4];
        #pragma unroll
        for (int c = 0; c < 4; ++c) bL[c] = pb3[32 * c + l31];
        #pragma unroll
        for (int t = 0; t < 2; ++t)
            #pragma unroll
            for (int c = 0; c < 4; ++c)
                #pragma unroll
                for (int r = 0; r < 16; ++r) acc[t][c][r] = bL[c];
    }
    #pragma unroll
    for (int s = 0; s < 8; ++s) {
        f16x8 wf[4];
        #pragma unroll
        for (int c = 0; c < 4; ++c)
            wf[c] = *(const f16x8*)((const char*)wA + swz(32 * c + l31, 2 * s + q));
        #pragma unroll
        for (int c = 0; c < 4; ++c) {
            acc[0][c] = __builtin_amdgcn_mfma_f32_32x32x16_f16(hf[0][s].v, wf[c], acc[0][c], 0, 0, 0);
            acc[1][c] = __builtin_amdgcn_mfma_f32_32x32x16_f16(hf[1][s].v, wf[c], acc[1][c], 0, 0, 0);
        }
    }

    // ---- pool: lane owns ch = 32c + l31; rows are pts; masked select ----
    #pragma unroll
    for (int c = 0; c < 4; ++c) {
        float s0 = 0.f;
        #pragma unroll
        for (int t = 0; t < 2; ++t) {
            const unsigned m = t ? mB : mA;
            #pragma unroll
            for (int r = 0; r < 16; ++r) {
                const int ptl = 4 * q + (r & 3) + 8 * (r >> 2);
                float v = fmaxf(acc[t][c][r], 0.f);
                s0 += ((m >> ptl) & 1u) ? v : 0.f;   // select, NaN-safe
            }
        }
        s0 += __shfl_xor(s0, 32);
        if (q == 0) atomicAdd(&pooled[b * 128 + 32 * c + l31], s0);
    }
}

// ---- rho: fp32 MLP on pooled [512][128] -> out [512] ----
__global__ __launch_bounds__(128) void rho_kernel(
    const float* __restrict__ pooled,
    const float* __restrict__ w0, const float* __restrict__ b0,
    const float* __restrict__ w1, const float* __restrict__ b1,
    const float* __restrict__ w2, const float* __restrict__ b2,
    const float* __restrict__ w3, const float* __restrict__ b3,
    float* __restrict__ out)
{
    __shared__ float buf[2][128];
    __shared__ float red[2];
    const int b = blockIdx.x, t = threadIdx.x;
    buf[0][t] = pooled[b * 128 + t];
    __syncthreads();
    const float* ws3[3] = {w0, w1, w2};
    const float* bs3[3] = {b0, b1, b2};
    int cur = 0;
    #pragma unroll 1
    for (int l = 0; l < 3; ++l) {
        float acc = bs3[l][t];
        const float* w = ws3[l];
        #pragma unroll 8
        for (int k = 0; k < 128; ++k)
            acc = fmaf(buf[cur][k], w[k * 128 + t], acc);
        buf[cur ^ 1][t] = fmaxf(acc, 0.f);
        cur ^= 1;
        __syncthreads();
    }
    float v = buf[cur][t] * w3[t];
    #pragma unroll
    for (int off = 32; off > 0; off >>= 1)
        v += __shfl_down(v, off, 64);
    if ((t & 63) == 0) red[t >> 6] = v;
    __syncthreads();
    if (t == 0) out[b] = red[0] + red[1] + b3[0];
}

extern "C" void kernel_launch(void* const* d_in, const int* in_sizes, int n_in,
                              void* d_out, int out_size, void* d_ws, size_t ws_size,
                              hipStream_t stream)
{
    (void)in_sizes; (void)n_in; (void)out_size; (void)ws_size;
    const float* x      = (const float*)d_in[0];
    const float* phi_w0 = (const float*)d_in[1];
    const float* phi_b0 = (const float*)d_in[2];
    const float* phi_w1 = (const float*)d_in[3];
    const float* phi_b1 = (const float*)d_in[4];
    const float* phi_w2 = (const float*)d_in[5];
    const float* phi_b2 = (const float*)d_in[6];
    const float* phi_w3 = (const float*)d_in[7];
    const float* phi_b3 = (const float*)d_in[8];
    const float* rho_w0 = (const float*)d_in[9];
    const float* rho_b0 = (const float*)d_in[10];
    const float* rho_w1 = (const float*)d_in[11];
    const float* rho_b1 = (const float*)d_in[12];
    const float* rho_w2 = (const float*)d_in[13];
    const float* rho_b2 = (const float*)d_in[14];
    const float* rho_w3 = (const float*)d_in[15];
    const float* rho_b3 = (const float*)d_in[16];

    float* pooled = (float*)d_ws;                          // 512*128*4 = 262144 B
    f16*   wtbuf  = (f16*)((char*)d_ws + 262144);          // 51200 f16 = 102400 B

    prep_kernel<<<256, 256, 0, stream>>>(phi_w0, phi_w1, phi_w2, phi_w3, wtbuf, pooled);
    phi_pool_kernel<<<4096, 256, 0, stream>>>(x, wtbuf, phi_b0, phi_b1, phi_b2, phi_b3, pooled);
    rho_kernel<<<B_, 128, 0, stream>>>(pooled, rho_w0, rho_b0, rho_w1, rho_b1,
                                       rho_w2, rho_b2, rho_w3, rho_b3, (float*)d_out);
}